// Round 5
// baseline (970.167 us; speedup 1.0000x reference)
//
#include <hip/hip_runtime.h>

// TransformerEncoder on MI355X (gfx950). ALL inputs/outputs are FLOAT32
// (per reference setup_inputs). Compute: bf16 MFMA (16x16x32), fp32 accum,
// fp32 global traffic; fp32->bf16 conversion happens during LDS staging.
// B=2, S=2048, E=1024, H=16, A=64, FF=4096. Tokens M = B*S = 4096.
//
// FFN algebra: relu comes AFTER the 2nd linear, so
//   ff = relu(mha@(W1@W2) + (b1@W2+b2)) = relu(mha@W12 + b12)
// -> W12 [1024x1024] precomputed per launch; FLOPs 137->86 GF total.
//
// Memory plan:
//   ws[0,16MB)        : res1 -> mha (in-place LN)        [4096x1024 f32]
//   ws[16,20MB)       : W12 [1024x1024 f32]
//   ws[20MB,+4KB)     : b12 [1024 f32]
//   d_out enc slot    : Q (head-major [H][tok][64] f32) -> attnH (flash writes
//                       IN-PLACE over its own Q tile) -> res2/ffout/encoded
//   d_out K/V slots   : final outputs (f32), read by flash.
//
// MFMA fragment layouts (verified per guide, 16x16x32 bf16):
//   A[m][k]: m=lane&15, k=(lane>>4)*8 + j
//   B[k][n]: n=lane&15, k=(lane>>4)*8 + j
//   C/D:     col=lane&15, row=(lane>>4)*4 + reg

typedef unsigned short u16;
typedef unsigned int u32;
typedef __bf16 bf16x8 __attribute__((ext_vector_type(8)));
typedef float f32x4 __attribute__((ext_vector_type(4)));

__device__ __forceinline__ u16 f2bf(float f) {
    u32 x = __float_as_uint(f);
    x += 0x7fffu + ((x >> 16) & 1u);
    return (u16)(x >> 16);
}

// ---------------------------------------------------------------- generic GEMM
// C[m,n] = sum_k Ain[m,k]*B[k,n] (+bias)(relu?)(+resid)(+resid2). fp32 I/O,
// bf16 MFMA compute. Ain = A (+ A2 elementwise, fused emb+pos).
// flags: 1 = relu (before residual adds), 2 = A is head-major [kk/64][token][64].
// Group mode (gsB!=0): blockIdx.y selects head: B += y*gsB, C += y*gsC, n0=0.
// C/resid/resid2 may alias (same-thread read-before-write only) — no __restrict__.
__launch_bounds__(256, 2)
__global__ void k_gemm(const float* A, const float* A2, const float* Bm, float* C,
                       int K, int lda, int ldb, int ldc,
                       long long gsB, long long gsC,
                       const float* bias, const float* resid, const float* resid2,
                       int flags) {
    __shared__ __align__(16) u16 As[64 * 72];
    __shared__ __align__(16) u16 Bs[64 * 72];
    const int tid = threadIdx.x;
    const int wave = tid >> 6, lane = tid & 63, quad = lane >> 4, l16 = lane & 15;
    const int m0 = blockIdx.x * 64;
    const float* Bp;
    float* Cp;
    int n0;
    if (gsB != 0) {
        n0 = 0;
        Bp = Bm + (long long)blockIdx.y * gsB;
        Cp = C + (long long)blockIdx.y * gsC;
    } else {
        n0 = blockIdx.y * 64;
        Bp = Bm;
        Cp = C;
    }

    f32x4 acc[4];
#pragma unroll
    for (int g = 0; g < 4; ++g) acc[g] = (f32x4){0.f, 0.f, 0.f, 0.f};

    for (int kk = 0; kk < K; kk += 64) {
        __syncthreads();
        // stage A tile [64m][64k]: fp32 float4 loads -> bf16 -> LDS (8B stores)
#pragma unroll
        for (int it = 0; it < 4; ++it) {
            const int slot = tid + it * 256;              // 0..1023
            const int row = slot >> 4, c4 = (slot & 15) * 4;
            long long off;
            if (flags & 2)
                off = (long long)(kk >> 6) * 262144LL + (long long)(m0 + row) * 64 + c4;
            else
                off = (long long)(m0 + row) * lda + kk + c4;
            float4 va = *(const float4*)(A + off);
            if (A2) {
                float4 vb = *(const float4*)(A2 + off);
                va.x += vb.x; va.y += vb.y; va.z += vb.z; va.w += vb.w;
            }
            ushort4 s;
            s.x = f2bf(va.x); s.y = f2bf(va.y); s.z = f2bf(va.z); s.w = f2bf(va.w);
            *(ushort4*)&As[row * 72 + c4] = s;
        }
        // stage B tile transposed: Bs[n][k], fp32 loads -> bf16 scatter
#pragma unroll
        for (int it = 0; it < 4; ++it) {
            const int slot = tid + it * 256;
            const int r = slot >> 4, c4 = (slot & 15) * 4;
            float4 v = *(const float4*)(Bp + (long long)(kk + r) * ldb + n0 + c4);
            Bs[(c4 + 0) * 72 + r] = f2bf(v.x);
            Bs[(c4 + 1) * 72 + r] = f2bf(v.y);
            Bs[(c4 + 2) * 72 + r] = f2bf(v.z);
            Bs[(c4 + 3) * 72 + r] = f2bf(v.w);
        }
        __syncthreads();
#pragma unroll
        for (int ks = 0; ks < 2; ++ks) {
            const bf16x8 af = *(const bf16x8*)&As[(wave * 16 + l16) * 72 + ks * 32 + quad * 8];
#pragma unroll
            for (int g = 0; g < 4; ++g) {
                const bf16x8 bf = *(const bf16x8*)&Bs[(g * 16 + l16) * 72 + ks * 32 + quad * 8];
                acc[g] = __builtin_amdgcn_mfma_f32_16x16x32_bf16(af, bf, acc[g], 0, 0, 0);
            }
        }
    }

    // epilogue: bias -> relu -> residuals -> fp32 store
#pragma unroll
    for (int g = 0; g < 4; ++g) {
#pragma unroll
        for (int r = 0; r < 4; ++r) {
            const int row = m0 + wave * 16 + quad * 4 + r;
            const int col = n0 + g * 16 + l16;
            float v = acc[g][r];
            if (bias) v += bias[col];
            if (flags & 1) v = fmaxf(v, 0.f);
            if (resid) v += resid[(long long)row * ldc + col];
            if (resid2) v += resid2[(long long)row * ldc + col];
            Cp[(long long)row * ldc + col] = v;
        }
    }
}

// ---------------------------------------------------------------- b12 = b1@W2 + b2
__global__ void k_b12(const float* __restrict__ b1, const float* __restrict__ W2,
                      const float* __restrict__ b2, float* __restrict__ b12) {
    const int o = blockIdx.x * 256 + threadIdx.x;  // 1024 outputs
    float s = 0.f;
    for (int f = 0; f < 4096; ++f) s += b1[f] * W2[f * 1024 + o];
    b12[o] = s + b2[o];
}

// ---------------------------------------------------------------- flash attention
// grid (S/64, H*B). Block: 64 q-rows (wave w owns rows w*16..+15), K/V tiles of 32.
// scores scale = 1/sqrt(E) = 1/32. Causal (k <= q). Online softmax.
// fp32 global I/O; bf16 staged in LDS. IN-PLACE: output overwrites this block's
// own Q tile (head-major chunk) after Q is staged; no other block reads it.
__launch_bounds__(256, 2)
__global__ void k_flash(float* Qa, const float* __restrict__ Kg, const float* __restrict__ Vg) {
    __shared__ __align__(16) u16 Qs[64 * 72];
    __shared__ __align__(16) u16 Ks[32 * 72];
    __shared__ __align__(16) u16 Vt[64 * 40];   // V transposed: Vt[a][s_k]
    __shared__ __align__(16) u16 Pb[4 * 16 * 40];
    const int tid = threadIdx.x;
    const int wave = tid >> 6, lane = tid & 63, quad = lane >> 4, l16 = lane & 15;
    const int hb = blockIdx.y, h = hb >> 1, b = hb & 1;
    const int q0 = blockIdx.x * 64;
    const long long base = (long long)h * 262144 + (long long)b * 131072;  // [h][b*S+s][64]
    float* Qp = Qa + base;
    const float* Kp = Kg + base;
    const float* Vp = Vg + base;
    const float NEG = -1.0e30f;

    // stage Q tile [64][64] fp32 -> bf16
#pragma unroll
    for (int it = 0; it < 4; ++it) {
        const int slot = tid + it * 256;
        const int row = slot >> 4, c4 = (slot & 15) * 4;
        float4 v = *(const float4*)(Qp + (long long)(q0 + row) * 64 + c4);
        ushort4 s;
        s.x = f2bf(v.x); s.y = f2bf(v.y); s.z = f2bf(v.z); s.w = f2bf(v.w);
        *(ushort4*)&Qs[row * 72 + c4] = s;
    }
    __syncthreads();
    bf16x8 aq0 = *(const bf16x8*)&Qs[(wave * 16 + l16) * 72 + quad * 8];
    bf16x8 aq1 = *(const bf16x8*)&Qs[(wave * 16 + l16) * 72 + 32 + quad * 8];

    f32x4 o[4];
#pragma unroll
    for (int g = 0; g < 4; ++g) o[g] = (f32x4){0.f, 0.f, 0.f, 0.f};
    float mrow[4] = {NEG, NEG, NEG, NEG};
    float lrow[4] = {0.f, 0.f, 0.f, 0.f};

    u16* Pw = Pb + wave * 16 * 40;
    const int nit = q0 / 32 + 2;  // k0 <= q0+63
    for (int it = 0; it < nit; ++it) {
        const int k0 = it * 32;
        __syncthreads();
        // stage K [32][64] and V transposed, fp32 -> bf16
#pragma unroll
        for (int st = 0; st < 2; ++st) {
            const int slot = tid + st * 256;              // 0..511
            const int row = slot >> 4, c4 = (slot & 15) * 4;
            float4 kv = *(const float4*)(Kp + (long long)(k0 + row) * 64 + c4);
            ushort4 s;
            s.x = f2bf(kv.x); s.y = f2bf(kv.y); s.z = f2bf(kv.z); s.w = f2bf(kv.w);
            *(ushort4*)&Ks[row * 72 + c4] = s;
            float4 vv = *(const float4*)(Vp + (long long)(k0 + row) * 64 + c4);
            Vt[(c4 + 0) * 40 + row] = f2bf(vv.x);
            Vt[(c4 + 1) * 40 + row] = f2bf(vv.y);
            Vt[(c4 + 2) * 40 + row] = f2bf(vv.z);
            Vt[(c4 + 3) * 40 + row] = f2bf(vv.w);
        }
        __syncthreads();
        // scores: S[q][s_k] = Q . K^T  (two 16-wide key groups)
        f32x4 s0 = (f32x4){0.f, 0.f, 0.f, 0.f};
        f32x4 s1 = (f32x4){0.f, 0.f, 0.f, 0.f};
        {
            const bf16x8 bk0a = *(const bf16x8*)&Ks[l16 * 72 + quad * 8];
            const bf16x8 bk0b = *(const bf16x8*)&Ks[l16 * 72 + 32 + quad * 8];
            s0 = __builtin_amdgcn_mfma_f32_16x16x32_bf16(aq0, bk0a, s0, 0, 0, 0);
            s0 = __builtin_amdgcn_mfma_f32_16x16x32_bf16(aq1, bk0b, s0, 0, 0, 0);
            const bf16x8 bk1a = *(const bf16x8*)&Ks[(16 + l16) * 72 + quad * 8];
            const bf16x8 bk1b = *(const bf16x8*)&Ks[(16 + l16) * 72 + 32 + quad * 8];
            s1 = __builtin_amdgcn_mfma_f32_16x16x32_bf16(aq0, bk1a, s1, 0, 0, 0);
            s1 = __builtin_amdgcn_mfma_f32_16x16x32_bf16(aq1, bk1b, s1, 0, 0, 0);
        }
        // online softmax per row (rows quad*4+r; 16 lanes of quad group hold cols)
        float p0[4], p1[4];
#pragma unroll
        for (int r = 0; r < 4; ++r) {
            const int qg = q0 + wave * 16 + quad * 4 + r;
            float v0 = s0[r] * 0.03125f;
            float v1 = s1[r] * 0.03125f;
            if (k0 + l16 > qg) v0 = NEG;
            if (k0 + 16 + l16 > qg) v1 = NEG;
            float tmax = fmaxf(v0, v1);
#pragma unroll
            for (int off = 1; off < 16; off <<= 1) tmax = fmaxf(tmax, __shfl_xor(tmax, off, 16));
            const float mo = mrow[r];
            const float mn = fmaxf(mo, tmax);
            const float alpha = __expf(mo - mn);
            const float e0 = __expf(v0 - mn);
            const float e1 = __expf(v1 - mn);
            float rs = e0 + e1;
#pragma unroll
            for (int off = 1; off < 16; off <<= 1) rs += __shfl_xor(rs, off, 16);
            lrow[r] = lrow[r] * alpha + rs;
            mrow[r] = mn;
            p0[r] = e0;
            p1[r] = e1;
#pragma unroll
            for (int g = 0; g < 4; ++g) o[g][r] *= alpha;
        }
        // P (C-layout) -> LDS -> A-layout
#pragma unroll
        for (int r = 0; r < 4; ++r) {
            Pw[(quad * 4 + r) * 40 + l16] = f2bf(p0[r]);
            Pw[(quad * 4 + r) * 40 + 16 + l16] = f2bf(p1[r]);
        }
        __syncthreads();
        const bf16x8 ap = *(const bf16x8*)&Pw[l16 * 40 + quad * 8];
#pragma unroll
        for (int g = 0; g < 4; ++g) {
            const bf16x8 bv = *(const bf16x8*)&Vt[(g * 16 + l16) * 40 + quad * 8];
            o[g] = __builtin_amdgcn_mfma_f32_16x16x32_bf16(ap, bv, o[g], 0, 0, 0);
        }
    }

    // epilogue: O /= l, fp32 write head-major IN-PLACE over this block's Q tile
#pragma unroll
    for (int r = 0; r < 4; ++r) {
        const float inv = 1.0f / lrow[r];
        const int srow = q0 + wave * 16 + quad * 4 + r;
#pragma unroll
        for (int g = 0; g < 4; ++g) {
            Qp[(long long)srow * 64 + g * 16 + l16] = o[g][r] * inv;
        }
    }
}

// ---------------------------------------------------------------- layernorm (row of 1024)
// out = LN(in1 (+ in2)) * g + be, fp32. May run IN-PLACE — no __restrict__.
__global__ void k_ln(const float* in1, const float* in2,
                     const float* __restrict__ g, const float* __restrict__ be,
                     float* out) {
    __shared__ float red[8];
    const int m = blockIdx.x;
    const int tid = threadIdx.x;
    const int e0 = tid * 4;
    const long long bp = (long long)m * 1024;
    float4 v = *(const float4*)(in1 + bp + e0);
    if (in2) {
        float4 u = *(const float4*)(in2 + bp + e0);
        v.x += u.x; v.y += u.y; v.z += u.z; v.w += u.w;
    }
    float s1 = v.x + v.y + v.z + v.w;
    float s2 = v.x * v.x + v.y * v.y + v.z * v.z + v.w * v.w;
#pragma unroll
    for (int off = 1; off < 64; off <<= 1) {
        s1 += __shfl_xor(s1, off);
        s2 += __shfl_xor(s2, off);
    }
    if ((tid & 63) == 0) {
        red[tid >> 6] = s1;
        red[4 + (tid >> 6)] = s2;
    }
    __syncthreads();
    const float S1 = red[0] + red[1] + red[2] + red[3];
    const float S2 = red[4] + red[5] + red[6] + red[7];
    const float mean = S1 * (1.0f / 1024.0f);
    const float var = S2 * (1.0f / 1024.0f) - mean * mean;
    const float rstd = rsqrtf(var + 1e-5f);
    float4 ug = *(const float4*)(g + e0);
    float4 ub = *(const float4*)(be + e0);
    float4 o;
    o.x = (v.x - mean) * rstd * ug.x + ub.x;
    o.y = (v.y - mean) * rstd * ug.y + ub.y;
    o.z = (v.z - mean) * rstd * ug.z + ub.z;
    o.w = (v.w - mean) * rstd * ug.w + ub.w;
    *(float4*)(out + bp + e0) = o;
}

// ---------------------------------------------------------------- launch
extern "C" void kernel_launch(void* const* d_in, const int* in_sizes, int n_in,
                              void* d_out, int out_size, void* d_ws, size_t ws_size,
                              hipStream_t stream) {
    (void)in_sizes; (void)n_in; (void)out_size; (void)ws_size;
    const float* emb    = (const float*)d_in[0];
    const float* pos    = (const float*)d_in[1];
    const float* Wq     = (const float*)d_in[2];
    const float* Wk     = (const float*)d_in[3];
    const float* Wv     = (const float*)d_in[4];
    const float* Wproj  = (const float*)d_in[5];
    const float* W1     = (const float*)d_in[6];
    const float* b1     = (const float*)d_in[7];
    const float* W2     = (const float*)d_in[8];
    const float* b2     = (const float*)d_in[9];
    const float* g_attn = (const float*)d_in[10];
    const float* be_attn= (const float*)d_in[11];
    const float* g_ffn  = (const float*)d_in[12];
    const float* be_ffn = (const float*)d_in[13];
    const float* g_out  = (const float*)d_in[14];
    const float* be_out = (const float*)d_in[15];

    float* enc   = (float*)d_out;          // Q -> attnH -> res2/ffout/encoded
    float* out_K = enc + 4194304;
    float* out_V = enc + 8388608;

    float* ws   = (float*)d_ws;
    float* res1 = ws;                      // [4096,1024] -> mha (in-place LN)
    float* mha  = ws;
    float* W12  = ws + 4194304;            // [1024,1024]
    float* b12  = ws + 5242880;            // [1024]

    // FFN weight composition (independent; run first)
    k_gemm<<<dim3(16, 16), 256, 0, stream>>>(W1, nullptr, W2, W12, 4096, 4096, 1024, 1024,
                                             0LL, 0LL, nullptr, nullptr, nullptr, 0);
    k_b12<<<4, 256, 0, stream>>>(b1, W2, b2, b12);

    // QKV (x = emb+pos fused into A staging). Q -> enc slot, K/V -> final outputs.
    k_gemm<<<dim3(64, 16), 256, 0, stream>>>(emb, pos, Wq, enc,   1024, 1024, 64, 64,
                                             65536LL, 262144LL, nullptr, nullptr, nullptr, 0);
    k_gemm<<<dim3(64, 16), 256, 0, stream>>>(emb, pos, Wk, out_K, 1024, 1024, 64, 64,
                                             65536LL, 262144LL, nullptr, nullptr, nullptr, 0);
    k_gemm<<<dim3(64, 16), 256, 0, stream>>>(emb, pos, Wv, out_V, 1024, 1024, 64, 64,
                                             65536LL, 262144LL, nullptr, nullptr, nullptr, 0);
    // flash attention, in-place over Q (head-major attnH in enc slot)
    k_flash<<<dim3(32, 32), 256, 0, stream>>>(enc, out_K, out_V);
    // res1 = attnH @ Wproj + emb + pos   (A head-major via flags=2)
    k_gemm<<<dim3(64, 16), 256, 0, stream>>>(enc, nullptr, Wproj, res1, 1024, 64, 1024, 1024,
                                             0LL, 0LL, nullptr, emb, pos, 2);
    k_ln<<<4096, 256, 0, stream>>>(res1, nullptr, g_attn, be_attn, mha);  // in-place
    // res2 = relu(mha @ W12 + b12) + mha  -> enc slot (attnH dead)
    k_gemm<<<dim3(64, 16), 256, 0, stream>>>(mha, nullptr, W12, enc, 1024, 1024, 1024, 1024,
                                             0LL, 0LL, b12, mha, nullptr, 1);
    k_ln<<<4096, 256, 0, stream>>>(enc, nullptr, g_ffn, be_ffn, enc);     // ffout in-place
    k_ln<<<4096, 256, 0, stream>>>(mha, enc, g_out, be_out, enc);         // encoded
}